// Round 10
// baseline (36.828 us; speedup 1.0000x reference)
//
#include <hip/hip_runtime.h>
#include <hip/hip_bf16.h>

// Problem constants (fixed by setup_inputs):
//   x: (64, 8192) f32   weight: (8192, 2048) f32
//   random_numbers: (4,) int (int32 or int64 storage, values in [1, 2^20))
//   y: (64, 8192) f32
#define K_FULL   8192
#define M_ROWS   64
#define N_OUT    8192
#define N_COMP   2048
#define P_MERS   2147483647

// ws layout:
//   [0, 256KB)        : xcF bf16 fragment-major (see below)
//   [256KB, 2.25MB)   : pbuf0 f32 [64][8192]  (k-half 0 partial)
//   [2.25MB, 4.25MB)  : pbuf1 f32 [64][8192]  (k-half 1 partial)
// xcF[((s*4 + g)*64 + lane)*8 + e] = xc[g*16 + (lane&15)][s*32 + (lane>>4)*8 + e]
//   (s = k-step 0..63, g = m-group 0..3) -> every A-fragment load is 64x16B contiguous.

typedef __attribute__((ext_vector_type(8))) short bf16x8;
typedef __attribute__((ext_vector_type(4))) float f32x4;

__device__ __forceinline__ short f2bfs(float f) {
    __hip_bfloat16 h = __float2bfloat16(f);
    return *reinterpret_cast<short*>(&h);
}
__device__ __forceinline__ unsigned int pk2bf(float a, float b) {
    return (unsigned int)(unsigned short)f2bfs(a)
         | ((unsigned int)(unsigned short)f2bfs(b) << 16);
}

__device__ __forceinline__ int hash_col(int j, int rn0, int rn1, int rn2, int rn3) {
    if (rn1 == 0 && rn3 == 0) {
        // int64 storage (JAX x64 on): exact hash; Mersenne fold (2^31 === 1 mod P)
        unsigned long long xx = (unsigned long long)(unsigned int)rn0 * (unsigned int)j
                              + (unsigned long long)(unsigned int)rn2;
        unsigned long long t = (xx & (unsigned long long)P_MERS) + (xx >> 31);
        if (t >= (unsigned long long)P_MERS) t -= (unsigned long long)P_MERS;
        return (int)(t & (N_COMP - 1));
    } else {
        // int32 storage (JAX x64 off): int32 wraparound + floored mod
        unsigned int t = (unsigned int)rn0 * (unsigned int)j + (unsigned int)rn1;
        int ti = (int)t;
        int m1 = ti % P_MERS;
        if (m1 < 0) m1 += P_MERS;
        return m1 & (N_COMP - 1);
    }
}

// Fused scatter+pack: block = one m row. LDS scatter-add, then pack bf16 into
// fragment-major xcF (scattered dword writes, 4KB/block -> negligible).
__global__ __launch_bounds__(1024) void k_xc(const float* __restrict__ x,
                                             const int* __restrict__ rn,
                                             unsigned int* __restrict__ xcF) {
    __shared__ float row[N_COMP];
    const int m = blockIdx.x;
    const int tid = threadIdx.x;
    row[tid] = 0.0f;
    row[tid + 1024] = 0.0f;
    const int rn0 = rn[0], rn1 = rn[1], rn2 = rn[2], rn3 = rn[3];
    __syncthreads();

    const float* xm = x + (size_t)m * K_FULL;
#pragma unroll
    for (int it = 0; it < 2; ++it) {
        int j0 = tid * 4 + it * 4096;
        float4 v = *(const float4*)(xm + j0);
        atomicAdd(&row[hash_col(j0 + 0, rn0, rn1, rn2, rn3)], v.x);
        atomicAdd(&row[hash_col(j0 + 1, rn0, rn1, rn2, rn3)], v.y);
        atomicAdd(&row[hash_col(j0 + 2, rn0, rn1, rn2, rn3)], v.z);
        atomicAdd(&row[hash_col(j0 + 3, rn0, rn1, rn2, rn3)], v.w);
    }
    __syncthreads();

    // pack c0=2*tid, c0+1 (same s,kg; adjacent e -> one dword)
    const int c0 = 2 * tid;
    const int s  = c0 >> 5;
    const int kg = (c0 >> 3) & 3;
    const int e0 = c0 & 7;
    const int g  = m >> 4;
    const int nr = m & 15;
    xcF[(((s * 4 + g) * 64 + kg * 16 + nr) << 2) + (e0 >> 1)] =
        pk2bf(row[c0], row[c0 + 1]);
}

// MFMA GEMM v6: grid 1024 = 512 n-tiles x 2 k-halves; 256 thr (4 waves).
// Block = 16 n-cols x 1024 k, 4 phases x 256 k. Per phase: W tile (16x256 f32)
// staged via 1KB-contiguous per-row wave loads -> bf16 LDS (double-buffered,
// prefetched one phase ahead); A-fragments issued at phase start from
// L2-resident fragment-major xcF; 8 MFMAs/wave/phase. 33KB LDS -> 4 blocks/CU
// (vs 2 before): 2x independent load streams per CU. Partials to pbuf[kb],
// summed by k_add (no atomics, deterministic).
#define NT    16
#define PH    4
#define PK    256
#define WROWD 132   // LDS W-row stride in dwords (528B = 33x16B aligned)

__global__ __launch_bounds__(256, 4) void k_gemm(const float* __restrict__ W,
                                                 const unsigned short* __restrict__ xcF,
                                                 float* __restrict__ pbuf) {
    __shared__ unsigned int wt[2][16 * WROWD];   // 2 x 8.25 KB
    __shared__ float ys[4][M_ROWS][NT];          // 16 KB
    const int tid  = threadIdx.x;
    const int lane = tid & 63;
    const int w    = __builtin_amdgcn_readfirstlane(tid >> 6);  // wave 0..3
    const int nr   = lane & 15;
    const int kg   = lane >> 4;
    const int nt   = blockIdx.x >> 1;
    const int kb   = blockIdx.x & 1;
    const int n0   = nt * NT;

    const float* wrow = W + (size_t)n0 * N_COMP + kb * 1024;  // + r*N_COMP + p*PK + lane*4

    // ---- prologue: stage phase 0 (wave w stages rows w*4..w*4+3)
#pragma unroll
    for (int i = 0; i < 4; ++i) {
        int r = w * 4 + i;
        float4 v = *(const float4*)(wrow + (size_t)r * N_COMP + lane * 4);
        uint2 pw = { pk2bf(v.x, v.y), pk2bf(v.z, v.w) };
        *(uint2*)&wt[0][r * WROWD + lane * 2] = pw;
    }
    __syncthreads();

    f32x4 acc0 = {0.f, 0.f, 0.f, 0.f};
    f32x4 acc1 = {0.f, 0.f, 0.f, 0.f};
    f32x4 acc2 = {0.f, 0.f, 0.f, 0.f};
    f32x4 acc3 = {0.f, 0.f, 0.f, 0.f};

#pragma unroll 1
    for (int p = 0; p < PH; ++p) {
        const int b = p & 1;
        // A-fragments for this phase: s = kb*32 + p*8 + w*2 + st (st=0,1)
        const unsigned short* abase =
            xcF + (size_t)(kb * 32 + p * 8 + w * 2) * 2048 + lane * 8;
        bf16x8 a00 = *(const bf16x8*)(abase);
        bf16x8 a01 = *(const bf16x8*)(abase + 512);
        bf16x8 a02 = *(const bf16x8*)(abase + 1024);
        bf16x8 a03 = *(const bf16x8*)(abase + 1536);
        bf16x8 a10 = *(const bf16x8*)(abase + 2048);
        bf16x8 a11 = *(const bf16x8*)(abase + 2048 + 512);
        bf16x8 a12 = *(const bf16x8*)(abase + 2048 + 1024);
        bf16x8 a13 = *(const bf16x8*)(abase + 2048 + 1536);
        // W loads for next phase (needed only after MFMAs)
        float4 nv0, nv1, nv2, nv3;
        if (p < PH - 1) {
            const float* wn = wrow + (p + 1) * PK + lane * 4;
            nv0 = *(const float4*)(wn + (size_t)(w * 4 + 0) * N_COMP);
            nv1 = *(const float4*)(wn + (size_t)(w * 4 + 1) * N_COMP);
            nv2 = *(const float4*)(wn + (size_t)(w * 4 + 2) * N_COMP);
            nv3 = *(const float4*)(wn + (size_t)(w * 4 + 3) * N_COMP);
        }
        // B fragments from LDS: row nr, k_local = w*64 + st*32 + kg*8 (shorts)
        const unsigned short* bbase =
            (const unsigned short*)wt[b] + nr * (WROWD * 2) + w * 64 + kg * 8;
        bf16x8 b0 = *(const bf16x8*)(bbase);
        bf16x8 b1 = *(const bf16x8*)(bbase + 32);
        acc0 = __builtin_amdgcn_mfma_f32_16x16x32_bf16(a00, b0, acc0, 0, 0, 0);
        acc1 = __builtin_amdgcn_mfma_f32_16x16x32_bf16(a01, b0, acc1, 0, 0, 0);
        acc2 = __builtin_amdgcn_mfma_f32_16x16x32_bf16(a02, b0, acc2, 0, 0, 0);
        acc3 = __builtin_amdgcn_mfma_f32_16x16x32_bf16(a03, b0, acc3, 0, 0, 0);
        acc0 = __builtin_amdgcn_mfma_f32_16x16x32_bf16(a10, b1, acc0, 0, 0, 0);
        acc1 = __builtin_amdgcn_mfma_f32_16x16x32_bf16(a11, b1, acc1, 0, 0, 0);
        acc2 = __builtin_amdgcn_mfma_f32_16x16x32_bf16(a12, b1, acc2, 0, 0, 0);
        acc3 = __builtin_amdgcn_mfma_f32_16x16x32_bf16(a13, b1, acc3, 0, 0, 0);
        if (p < PH - 1) {
            uint2 p0 = { pk2bf(nv0.x, nv0.y), pk2bf(nv0.z, nv0.w) };
            uint2 p1 = { pk2bf(nv1.x, nv1.y), pk2bf(nv1.z, nv1.w) };
            uint2 p2 = { pk2bf(nv2.x, nv2.y), pk2bf(nv2.z, nv2.w) };
            uint2 p3 = { pk2bf(nv3.x, nv3.y), pk2bf(nv3.z, nv3.w) };
            *(uint2*)&wt[b ^ 1][(w * 4 + 0) * WROWD + lane * 2] = p0;
            *(uint2*)&wt[b ^ 1][(w * 4 + 1) * WROWD + lane * 2] = p1;
            *(uint2*)&wt[b ^ 1][(w * 4 + 2) * WROWD + lane * 2] = p2;
            *(uint2*)&wt[b ^ 1][(w * 4 + 3) * WROWD + lane * 2] = p3;
        }
        __syncthreads();
    }

    // C/D layout (m89-verified): col = lane&15, row = (lane>>4)*4 + j
#pragma unroll
    for (int j = 0; j < 4; ++j) {
        ys[w][ 0 + kg * 4 + j][nr] = acc0[j];
        ys[w][16 + kg * 4 + j][nr] = acc1[j];
        ys[w][32 + kg * 4 + j][nr] = acc2[j];
        ys[w][48 + kg * 4 + j][nr] = acc3[j];
    }
    __syncthreads();

    // reduce 4 wave-partials -> pbuf[kb], 4 outputs per thread
    float* pb = pbuf + (size_t)kb * M_ROWS * N_OUT;
#pragma unroll
    for (int i = 0; i < 4; ++i) {
        int o = tid + 256 * i;
        int m = o >> 4;
        int n = o & 15;
        float s = ys[0][m][n] + ys[1][m][n] + ys[2][m][n] + ys[3][m][n];
        pb[(size_t)m * N_OUT + n0 + n] = s;
    }
}

// y = pbuf0 + pbuf1 (vectorized, deterministic)
__global__ __launch_bounds__(256) void k_add(const float* __restrict__ pbuf,
                                             float* __restrict__ y) {
    int i = blockIdx.x * 256 + threadIdx.x;   // < 131072 float4
    const float4* p0 = (const float4*)pbuf;
    const float4* p1 = (const float4*)(pbuf + (size_t)M_ROWS * N_OUT);
    float4 a = p0[i], b = p1[i];
    float4 r = { a.x + b.x, a.y + b.y, a.z + b.z, a.w + b.w };
    ((float4*)y)[i] = r;
}

extern "C" void kernel_launch(void* const* d_in, const int* in_sizes, int n_in,
                              void* d_out, int out_size, void* d_ws, size_t ws_size,
                              hipStream_t stream) {
    const float* x = (const float*)d_in[0];
    const float* W = (const float*)d_in[1];
    const int* rn  = (const int*)d_in[2];
    float* y       = (float*)d_out;

    unsigned int* xcF = (unsigned int*)d_ws;
    float* pbuf       = (float*)((char*)d_ws + 256 * 1024);

    k_xc<<<M_ROWS, 1024, 0, stream>>>(x, rn, xcF);
    k_gemm<<<1024, 256, 0, stream>>>(W, (const unsigned short*)xcF, pbuf);
    k_add<<<512, 256, 0, stream>>>(pbuf, y);
}

// Round 11
// 30.677 us; speedup vs baseline: 1.2005x; 1.2005x over previous
//
#include <hip/hip_runtime.h>
#include <hip/hip_bf16.h>

// Problem constants (fixed by setup_inputs):
//   x: (64, 8192) f32   weight: (8192, 2048) f32
//   random_numbers: (4,) int (int32 or int64 storage, values in [1, 2^20))
//   y: (64, 8192) f32
#define K_FULL   8192
#define M_ROWS   64
#define N_OUT    8192
#define N_COMP   2048
#define P_MERS   2147483647

// ws layout: [0, 256KB) : xcF bf16, fragment-major:
//   xcF[((s*4 + g)*64 + lane)*8 + e] = xc[g*16 + (lane&15)][s*32 + (lane>>4)*8 + e]
//   (s = k-step 0..63, g = m-group 0..3) -> every A-fragment load is 64x16B contiguous.

typedef __attribute__((ext_vector_type(8))) short bf16x8;
typedef __attribute__((ext_vector_type(4))) float f32x4;

__device__ __forceinline__ short f2bfs(float f) {
    __hip_bfloat16 h = __float2bfloat16(f);
    return *reinterpret_cast<short*>(&h);
}
__device__ __forceinline__ unsigned int pk2bf(float a, float b) {
    return (unsigned int)(unsigned short)f2bfs(a)
         | ((unsigned int)(unsigned short)f2bfs(b) << 16);
}

__device__ __forceinline__ int hash_col(int j, int rn0, int rn1, int rn2, int rn3) {
    if (rn1 == 0 && rn3 == 0) {
        // int64 storage (JAX x64 on): exact hash; Mersenne fold (2^31 === 1 mod P)
        unsigned long long xx = (unsigned long long)(unsigned int)rn0 * (unsigned int)j
                              + (unsigned long long)(unsigned int)rn2;
        unsigned long long t = (xx & (unsigned long long)P_MERS) + (xx >> 31);
        if (t >= (unsigned long long)P_MERS) t -= (unsigned long long)P_MERS;
        return (int)(t & (N_COMP - 1));
    } else {
        // int32 storage (JAX x64 off): int32 wraparound + floored mod
        unsigned int t = (unsigned int)rn0 * (unsigned int)j + (unsigned int)rn1;
        int ti = (int)t;
        int m1 = ti % P_MERS;
        if (m1 < 0) m1 += P_MERS;
        return m1 & (N_COMP - 1);
    }
}

// Fused scatter+pack: block = one m row. LDS scatter-add, then pack bf16 into
// fragment-major xcF (scattered dword writes, 4KB/block -> negligible).
__global__ __launch_bounds__(1024) void k_xc(const float* __restrict__ x,
                                             const int* __restrict__ rn,
                                             unsigned int* __restrict__ xcF) {
    __shared__ float row[N_COMP];
    const int m = blockIdx.x;
    const int tid = threadIdx.x;
    row[tid] = 0.0f;
    row[tid + 1024] = 0.0f;
    const int rn0 = rn[0], rn1 = rn[1], rn2 = rn[2], rn3 = rn[3];
    __syncthreads();

    const float* xm = x + (size_t)m * K_FULL;
#pragma unroll
    for (int it = 0; it < 2; ++it) {
        int j0 = tid * 4 + it * 4096;
        float4 v = *(const float4*)(xm + j0);
        atomicAdd(&row[hash_col(j0 + 0, rn0, rn1, rn2, rn3)], v.x);
        atomicAdd(&row[hash_col(j0 + 1, rn0, rn1, rn2, rn3)], v.y);
        atomicAdd(&row[hash_col(j0 + 2, rn0, rn1, rn2, rn3)], v.z);
        atomicAdd(&row[hash_col(j0 + 3, rn0, rn1, rn2, rn3)], v.w);
    }
    __syncthreads();

    // pack c0=2*tid, c0+1 (same s,kg; adjacent e -> one dword)
    const int c0 = 2 * tid;
    const int s  = c0 >> 5;
    const int kg = (c0 >> 3) & 3;
    const int e0 = c0 & 7;
    const int g  = m >> 4;
    const int nr = m & 15;
    xcF[(((s * 4 + g) * 64 + kg * 16 + nr) << 2) + (e0 >> 1)] =
        pk2bf(row[c0], row[c0 + 1]);
}

// MFMA GEMM v7 = R8 + per-block k-phase rotation (channel spread).
// Block = 16 n-cols x all 2048 k, 512 thr (8 waves), 8 phases x 256 k.
// Block b processes phases in order (p + rot) & 7, rot = (b>>3) & 7, so at any
// instant the chip's W reads cover all 8 k-window alignment classes (mod 8KB)
// instead of one -> full HBM channel utilization. Accumulation commutes;
// fp order fixed per block -> deterministic.
#define WROWD 132   // LDS W-tile row stride in dwords (528B, 16B-aligned)

__global__ __launch_bounds__(512) void k_gemm(const float* __restrict__ W,
                                              const unsigned short* __restrict__ xcF,
                                              float* __restrict__ y) {
    __shared__ unsigned int wt[2][16 * WROWD];   // 2 x 8.25 KB
    __shared__ float ys[8][M_ROWS][16];          // 32 KB
    const int tid  = threadIdx.x;
    const int lane = tid & 63;
    const int w    = __builtin_amdgcn_readfirstlane(tid >> 6);  // wave 0..7
    const int nr   = lane & 15;
    const int kg   = lane >> 4;
    const int n0   = blockIdx.x * 16;
    const int rot  = (blockIdx.x >> 3) & 7;      // phase rotation
    const int r0   = 2 * w;                      // rows staged by this wave

    const float* wrow = W + (size_t)(n0 + r0) * N_COMP;   // + pm*256 + lane*4
    const unsigned short* ab = xcF + (size_t)w * 2048 + lane * 8;

    f32x4 acc0 = {0.f, 0.f, 0.f, 0.f};
    f32x4 acc1 = {0.f, 0.f, 0.f, 0.f};
    f32x4 acc2 = {0.f, 0.f, 0.f, 0.f};
    f32x4 acc3 = {0.f, 0.f, 0.f, 0.f};

    // ---- prologue: stage memory-phase rot into buffer 0
    {
        float4 va = *(const float4*)(wrow + rot * 256 + lane * 4);
        float4 vb = *(const float4*)(wrow + rot * 256 + N_COMP + lane * 4);
        uint2 pa = { pk2bf(va.x, va.y), pk2bf(va.z, va.w) };
        uint2 pb = { pk2bf(vb.x, vb.y), pk2bf(vb.z, vb.w) };
        *(uint2*)&wt[0][r0 * WROWD + lane * 2]       = pa;
        *(uint2*)&wt[0][(r0 + 1) * WROWD + lane * 2] = pb;
    }
    // prefetch A for memory-phase rot (k-step s = rot*8 + w)
    const unsigned short* ap0 = ab + (size_t)rot * 16384;
    bf16x8 a0 = *(const bf16x8*)(ap0);
    bf16x8 a1 = *(const bf16x8*)(ap0 + 512);
    bf16x8 a2 = *(const bf16x8*)(ap0 + 1024);
    bf16x8 a3 = *(const bf16x8*)(ap0 + 1536);
    __syncthreads();

#pragma unroll 1
    for (int p = 0; p < 8; ++p) {
        const int b  = p & 1;
        const int pn = (p + 1 + rot) & 7;   // next memory phase
        float4 nva, nvb;
        bf16x8 na0, na1, na2, na3;
        if (p < 7) {
            // issue next-phase global loads early
            nva = *(const float4*)(wrow + pn * 256 + lane * 4);
            nvb = *(const float4*)(wrow + pn * 256 + N_COMP + lane * 4);
            const unsigned short* nab = ab + (size_t)pn * 16384;
            na0 = *(const bf16x8*)(nab);
            na1 = *(const bf16x8*)(nab + 512);
            na2 = *(const bf16x8*)(nab + 1024);
            na3 = *(const bf16x8*)(nab + 1536);
        }
        // compute current phase: B fragment from LDS, k-local = w*32 + kg*8 shorts
        bf16x8 bf = *(const bf16x8*)((const unsigned short*)&wt[b][0]
                                     + nr * (WROWD * 2) + w * 32 + kg * 8);
        acc0 = __builtin_amdgcn_mfma_f32_16x16x32_bf16(a0, bf, acc0, 0, 0, 0);
        acc1 = __builtin_amdgcn_mfma_f32_16x16x32_bf16(a1, bf, acc1, 0, 0, 0);
        acc2 = __builtin_amdgcn_mfma_f32_16x16x32_bf16(a2, bf, acc2, 0, 0, 0);
        acc3 = __builtin_amdgcn_mfma_f32_16x16x32_bf16(a3, bf, acc3, 0, 0, 0);
        if (p < 7) {
            uint2 pa = { pk2bf(nva.x, nva.y), pk2bf(nva.z, nva.w) };
            uint2 pb = { pk2bf(nvb.x, nvb.y), pk2bf(nvb.z, nvb.w) };
            *(uint2*)&wt[b ^ 1][r0 * WROWD + lane * 2]       = pa;
            *(uint2*)&wt[b ^ 1][(r0 + 1) * WROWD + lane * 2] = pb;
            a0 = na0; a1 = na1; a2 = na2; a3 = na3;
        }
        __syncthreads();
    }

    // C/D layout (m89-verified): col = lane&15, row = (lane>>4)*4 + j
#pragma unroll
    for (int j = 0; j < 4; ++j) {
        ys[w][ 0 + kg * 4 + j][nr] = acc0[j];
        ys[w][16 + kg * 4 + j][nr] = acc1[j];
        ys[w][32 + kg * 4 + j][nr] = acc2[j];
        ys[w][48 + kg * 4 + j][nr] = acc3[j];
    }
    __syncthreads();

    // reduce 8 k-slices, direct store: 1024 outputs, 2 per thread
#pragma unroll
    for (int i = 0; i < 2; ++i) {
        int o = tid + 512 * i;
        int m = o >> 4;
        int n = o & 15;
        float s = 0.f;
#pragma unroll
        for (int q = 0; q < 8; ++q) s += ys[q][m][n];
        y[(size_t)m * N_OUT + n0 + n] = s;
    }
}

extern "C" void kernel_launch(void* const* d_in, const int* in_sizes, int n_in,
                              void* d_out, int out_size, void* d_ws, size_t ws_size,
                              hipStream_t stream) {
    const float* x = (const float*)d_in[0];
    const float* W = (const float*)d_in[1];
    const int* rn  = (const int*)d_in[2];
    float* y       = (float*)d_out;

    unsigned int* xcF = (unsigned int*)d_ws;

    k_xc<<<M_ROWS, 1024, 0, stream>>>(x, rn, xcF);
    k_gemm<<<N_OUT / 16, 512, 0, stream>>>(W, (const unsigned short*)xcF, y);
}